// Round 12
// baseline (455.807 us; speedup 1.0000x reference)
//
#include <hip/hip_runtime.h>
#include <stdint.h>

#define B_ 1024
#define T_ 512
#define F_ 64
#define H_ 32
#define G_ 128  // 4H

typedef __attribute__((ext_vector_type(8))) short bf16x8;
typedef __attribute__((ext_vector_type(4))) float f32x4;

__device__ __forceinline__ uint32_t bf16r(float f) {
  uint32_t u = __builtin_bit_cast(uint32_t, f);
  return (u + 0x7fffu + ((u >> 16) & 1u)) >> 16;  // RNE bf16
}
__device__ __forceinline__ float rl(float v, int l) {
  return __builtin_bit_cast(float, __builtin_amdgcn_readlane(__builtin_bit_cast(int, v), l));
}
__device__ __forceinline__ float fsig(float x) { return 1.f / (1.f + __expf(-x)); }
__device__ __forceinline__ float ftanh(float x) { return 2.f / (1.f + __expf(-2.f * x)) - 1.f; }
__device__ __forceinline__ float bflo(uint32_t d) { return __builtin_bit_cast(float, d << 16); }
__device__ __forceinline__ float bfhi(uint32_t d) { return __builtin_bit_cast(float, d & 0xffff0000u); }

#define MFMA16(a, b, c) __builtin_amdgcn_mfma_f32_16x16x32_bf16((a), (b), (c), 0, 0, 0)

// ---------------------------------------------------------------------------
// K1 (MFMA, unchanged — verified r6/r7): xg = pack_bf16(tanh(x@Wenc+benc)@kern+bias)
// ---------------------------------------------------------------------------
__global__ __launch_bounds__(256, 3) void k1_mfma(
    const float* __restrict__ x, const float* __restrict__ Wenc,
    const float* __restrict__ benc, const float* __restrict__ kern,
    const float* __restrict__ bias, uint32_t* __restrict__ xg) {
  __shared__ unsigned short sWt[64 * 72];   // Wenc^T bf16 [n][k], stride 72
  __shared__ unsigned short sKt[128 * 72];  // kern^T bf16 [n][k]
  __shared__ unsigned short sE[128 * 72];   // enc bf16 [row][k]
  const int tid = threadIdx.x;
  const int lane = tid & 63;
  const int w = tid >> 6;       // wave 0..3 -> rows w*32..w*32+31
  const int m = lane & 15;
  const int g = lane >> 4;      // 0..3
  const int r0 = blockIdx.x * 128;

  {  // stage Wenc^T and kern^T as bf16 (one-time)
    const int r = tid & 63;
    const int c0 = (tid >> 6) * 16;
#pragma unroll
    for (int q = 0; q < 4; ++q) {
      float4 v = *(const float4*)(Wenc + (size_t)r * F_ + c0 + q * 4);
      sWt[(c0 + q * 4 + 0) * 72 + r] = (unsigned short)bf16r(v.x);
      sWt[(c0 + q * 4 + 1) * 72 + r] = (unsigned short)bf16r(v.y);
      sWt[(c0 + q * 4 + 2) * 72 + r] = (unsigned short)bf16r(v.z);
      sWt[(c0 + q * 4 + 3) * 72 + r] = (unsigned short)bf16r(v.w);
    }
    const int d0 = (tid >> 6) * 32;
#pragma unroll
    for (int q = 0; q < 8; ++q) {
      float4 v = *(const float4*)(kern + (size_t)r * G_ + d0 + q * 4);
      sKt[(d0 + q * 4 + 0) * 72 + r] = (unsigned short)bf16r(v.x);
      sKt[(d0 + q * 4 + 1) * 72 + r] = (unsigned short)bf16r(v.y);
      sKt[(d0 + q * 4 + 2) * 72 + r] = (unsigned short)bf16r(v.z);
      sKt[(d0 + q * 4 + 3) * 72 + r] = (unsigned short)bf16r(v.w);
    }
  }
  __syncthreads();

  bf16x8 a[2][2];
#pragma unroll
  for (int rt = 0; rt < 2; ++rt)
#pragma unroll
    for (int kh = 0; kh < 2; ++kh) {
      const float* xr = x + (size_t)(r0 + w * 32 + rt * 16 + m) * F_ + kh * 32 + g * 8;
      float4 v0 = ((const float4*)xr)[0];
      float4 v1 = ((const float4*)xr)[1];
      bf16x8 t;
      t[0] = (short)bf16r(v0.x); t[1] = (short)bf16r(v0.y);
      t[2] = (short)bf16r(v0.z); t[3] = (short)bf16r(v0.w);
      t[4] = (short)bf16r(v1.x); t[5] = (short)bf16r(v1.y);
      t[6] = (short)bf16r(v1.z); t[7] = (short)bf16r(v1.w);
      a[rt][kh] = t;
    }

#pragma unroll
  for (int ct = 0; ct < 4; ++ct) {
    float be = benc[ct * 16 + m];
    f32x4 acc0 = {be, be, be, be};
    f32x4 acc1 = {be, be, be, be};
    bf16x8 b0 = *(const bf16x8*)&sWt[(ct * 16 + m) * 72 + g * 8];
    bf16x8 b1 = *(const bf16x8*)&sWt[(ct * 16 + m) * 72 + 32 + g * 8];
    acc0 = MFMA16(a[0][0], b0, acc0);
    acc0 = MFMA16(a[0][1], b1, acc0);
    acc1 = MFMA16(a[1][0], b0, acc1);
    acc1 = MFMA16(a[1][1], b1, acc1);
#pragma unroll
    for (int r4 = 0; r4 < 4; ++r4) {
      sE[(w * 32 + g * 4 + r4) * 72 + ct * 16 + m] =
          (unsigned short)bf16r(ftanh(acc0[r4]));
      sE[(w * 32 + 16 + g * 4 + r4) * 72 + ct * 16 + m] =
          (unsigned short)bf16r(ftanh(acc1[r4]));
    }
  }
  __syncthreads();

  bf16x8 e[2][2];
#pragma unroll
  for (int rt = 0; rt < 2; ++rt)
#pragma unroll
    for (int kh = 0; kh < 2; ++kh)
      e[rt][kh] = *(const bf16x8*)&sE[(w * 32 + rt * 16 + m) * 72 + kh * 32 + g * 8];

#pragma unroll
  for (int ctp = 0; ctp < 4; ++ctp) {
    float blo = bias[ctp * 16 + m];
    float bhi = bias[64 + ctp * 16 + m];
    f32x4 lo0 = {blo, blo, blo, blo}, lo1 = {blo, blo, blo, blo};
    f32x4 hi0 = {bhi, bhi, bhi, bhi}, hi1 = {bhi, bhi, bhi, bhi};
    bf16x8 bl0 = *(const bf16x8*)&sKt[(ctp * 16 + m) * 72 + g * 8];
    bf16x8 bl1 = *(const bf16x8*)&sKt[(ctp * 16 + m) * 72 + 32 + g * 8];
    bf16x8 bh0 = *(const bf16x8*)&sKt[(64 + ctp * 16 + m) * 72 + g * 8];
    bf16x8 bh1 = *(const bf16x8*)&sKt[(64 + ctp * 16 + m) * 72 + 32 + g * 8];
    lo0 = MFMA16(e[0][0], bl0, lo0);  lo0 = MFMA16(e[0][1], bl1, lo0);
    lo1 = MFMA16(e[1][0], bl0, lo1);  lo1 = MFMA16(e[1][1], bl1, lo1);
    hi0 = MFMA16(e[0][0], bh0, hi0);  hi0 = MFMA16(e[0][1], bh1, hi0);
    hi1 = MFMA16(e[1][0], bh0, hi1);  hi1 = MFMA16(e[1][1], bh1, hi1);
#pragma unroll
    for (int r4 = 0; r4 < 4; ++r4) {
      int row0 = r0 + w * 32 + g * 4 + r4;
      xg[(size_t)row0 * 64 + ctp * 16 + m] =
          bf16r(lo0[r4]) | (bf16r(hi0[r4]) << 16);
      int row1 = row0 + 16;
      xg[(size_t)row1 * 64 + ctp * 16 + m] =
          bf16r(lo1[r4]) | (bf16r(hi1[r4]) << 16);
    }
  }
}

// ---------------------------------------------------------------------------
// K2: LSTM scan, TWO batches per wave, chains interleaved. Grid-capped at
// 1 wave/SIMD means latency gaps can only be filled by a second independent
// chain inside the wave (r10: 1700 cyc/step, only 38% VALU issue).
// Per-batch numerics identical to the verified r10 kernel.
// ---------------------------------------------------------------------------
__global__ __launch_bounds__(64, 1) void k2_scan(
    const uint32_t* __restrict__ xgin, float* __restrict__ hout,
    const float* __restrict__ rec) {
  const int lane = threadIdx.x;
  const int b0 = blockIdx.x * 2;
  const bool lo32 = (lane < 32);

  float rA[H_], rB[H_];
#pragma unroll
  for (int k = 0; k < H_; ++k) {
    rA[k] = rec[k * G_ + lane];        // columns 0..63   (i|f)
    rB[k] = rec[k * G_ + 64 + lane];   // columns 64..127 (g|o)
  }

  const uint32_t* xpA = xgin + (size_t)b0 * (T_ * 64) + lane;
  const uint32_t* xpB = xpA + T_ * 64;
  float* hsA = hout + (size_t)b0 * (T_ * 64);
  float* hsB = hsA + T_ * 64;

  float hA = 0.f, cA = 0.f;
  float hB = 0.f, cB = 0.f;

  auto step = [&](uint32_t wA, uint32_t wB, int t) {
    float zA1a = bflo(wA), zA2a = bfhi(wA);
    float zB1a = bflo(wB), zB2a = bfhi(wB);
    float zA1b = 0.f, zA1c = 0.f, zA1d = 0.f;
    float zA2b = 0.f, zA2c = 0.f, zA2d = 0.f;
    float zB1b = 0.f, zB1c = 0.f, zB1d = 0.f;
    float zB2b = 0.f, zB2c = 0.f, zB2d = 0.f;
#pragma unroll
    for (int k4 = 0; k4 < 8; ++k4) {
      float sA0 = rl(hA, 4 * k4 + 0), sB0 = rl(hB, 4 * k4 + 0);
      float sA1 = rl(hA, 4 * k4 + 1), sB1 = rl(hB, 4 * k4 + 1);
      float sA2 = rl(hA, 4 * k4 + 2), sB2 = rl(hB, 4 * k4 + 2);
      float sA3 = rl(hA, 4 * k4 + 3), sB3 = rl(hB, 4 * k4 + 3);
      zA1a = fmaf(sA0, rA[4 * k4 + 0], zA1a); zA2a = fmaf(sA0, rB[4 * k4 + 0], zA2a);
      zB1a = fmaf(sB0, rA[4 * k4 + 0], zB1a); zB2a = fmaf(sB0, rB[4 * k4 + 0], zB2a);
      zA1b = fmaf(sA1, rA[4 * k4 + 1], zA1b); zA2b = fmaf(sA1, rB[4 * k4 + 1], zA2b);
      zB1b = fmaf(sB1, rA[4 * k4 + 1], zB1b); zB2b = fmaf(sB1, rB[4 * k4 + 1], zB2b);
      zA1c = fmaf(sA2, rA[4 * k4 + 2], zA1c); zA2c = fmaf(sA2, rB[4 * k4 + 2], zA2c);
      zB1c = fmaf(sB2, rA[4 * k4 + 2], zB1c); zB2c = fmaf(sB2, rB[4 * k4 + 2], zB2c);
      zA1d = fmaf(sA3, rA[4 * k4 + 3], zA1d); zA2d = fmaf(sA3, rB[4 * k4 + 3], zA2d);
      zB1d = fmaf(sB3, rA[4 * k4 + 3], zB1d); zB2d = fmaf(sB3, rB[4 * k4 + 3], zB2d);
    }
    float zA1 = (zA1a + zA1b) + (zA1c + zA1d);
    float zA2 = (zA2a + zA2b) + (zA2c + zA2d);
    float zB1 = (zB1a + zB1b) + (zB1c + zB1d);
    float zB2 = (zB2a + zB2b) + (zB2c + zB2d);

    float act1A = fsig(zA1);                     // i (lanes<32) | f (lanes>=32)
    float act1B = fsig(zB1);
    float xxA = lo32 ? 2.f * zA2 : zA2;
    float xxB = lo32 ? 2.f * zB2 : zB2;
    float sgA = fsig(xxA);
    float sgB = fsig(xxB);
    float act2A = lo32 ? 2.f * sgA - 1.f : sgA;  // tanh(g) | sigmoid(o)
    float act2B = lo32 ? 2.f * sgB - 1.f : sgB;

    float fA = __shfl(act1A, lane | 32);         // f on all lanes (VERIFIED)
    float fB = __shfl(act1B, lane | 32);
    float oA = __shfl(act2A, lane | 32);         // o on all lanes
    float oB = __shfl(act2B, lane | 32);

    cA = fA * cA + act1A * act2A;                // valid on lanes<32
    cB = fB * cB + act1B * act2B;
    float tcA = ftanh(cA);
    float tcB = ftanh(cB);
    hA = oA * tcA;
    hB = oB * tcB;

    if (lo32) {                                  // fp32 h into dead slot region
      hsA[(size_t)t * 64 + lane] = hA;
      hsB[(size_t)t * 64 + lane] = hB;
    }
  };

  uint32_t pA[4], pB[4];
#pragma unroll
  for (int i = 0; i < 4; ++i) { pA[i] = xpA[i * 64]; pB[i] = xpB[i * 64]; }
  for (int tb = 0; tb < T_; tb += 4) {
    uint32_t nA[4], nB[4];
#pragma unroll
    for (int i = 0; i < 4; ++i) {               // tail wrap reads unused
      nA[i] = xpA[((tb + 4 + i) & 511) * 64];
      nB[i] = xpB[((tb + 4 + i) & 511) * 64];
    }
#pragma unroll
    for (int i = 0; i < 4; ++i) step(pA[i], pB[i], tb + i);
#pragma unroll
    for (int i = 0; i < 4; ++i) { pA[i] = nA[i]; pB[i] = nB[i]; }
  }
}

// ---------------------------------------------------------------------------
// K3 (unchanged — verified r7, spill-free).
// ---------------------------------------------------------------------------
__global__ __launch_bounds__(256, 4) void k3_attn(
    const uint32_t* __restrict__ xg,
    const float* __restrict__ attnW, const float* __restrict__ attnB,
    const float* __restrict__ attnU, const float* __restrict__ Wdec,
    const float* __restrict__ bdec, float* __restrict__ out) {
  __shared__ float sSc[T_];
  __shared__ float sRed[8];
  __shared__ float sP[8][H_];
  const int tid = threadIdx.x;
  const int b = blockIdx.x;

  const uint32_t* hbase = xg + (size_t)b * (T_ * 64);

  float mysc[2];
#pragma unroll
  for (int q = 0; q < 2; ++q) {
    int t = tid + q * 256;
    const float4* hp = (const float4*)(hbase + (size_t)t * 64);

    float hv[H_];
#pragma unroll
    for (int i = 0; i < 8; ++i) {
      float4 v = hp[i];
      hv[4 * i + 0] = v.x; hv[4 * i + 1] = v.y;
      hv[4 * i + 2] = v.z; hv[4 * i + 3] = v.w;
    }

    float lat[H_];
#pragma unroll
    for (int j4 = 0; j4 < 8; ++j4) {
      float4 bv = ((const float4*)attnB)[j4];  // uniform -> s_load
      lat[4 * j4 + 0] = bv.x; lat[4 * j4 + 1] = bv.y;
      lat[4 * j4 + 2] = bv.z; lat[4 * j4 + 3] = bv.w;
    }
#pragma unroll
    for (int d = 0; d < H_; ++d) {
      float hd = hv[d];
      const float4* wr = (const float4*)(attnW + d * H_);  // uniform -> s_load
#pragma unroll
      for (int j4 = 0; j4 < 8; ++j4) {
        float4 w = wr[j4];
        lat[4 * j4 + 0] += hd * w.x;
        lat[4 * j4 + 1] += hd * w.y;
        lat[4 * j4 + 2] += hd * w.z;
        lat[4 * j4 + 3] += hd * w.w;
      }
    }
    float sc = 0.f;
#pragma unroll
    for (int j = 0; j < H_; ++j) sc += ftanh(lat[j]) * attnU[j];
    mysc[q] = sc;
  }

  float m2 = fmaxf(mysc[0], mysc[1]);
  m2 = fmaxf(m2, __shfl_xor(m2, 1));  m2 = fmaxf(m2, __shfl_xor(m2, 2));
  m2 = fmaxf(m2, __shfl_xor(m2, 4));  m2 = fmaxf(m2, __shfl_xor(m2, 8));
  m2 = fmaxf(m2, __shfl_xor(m2, 16)); m2 = fmaxf(m2, __shfl_xor(m2, 32));
  if ((tid & 63) == 0) sRed[tid >> 6] = m2;
  __syncthreads();
  float m = fmaxf(fmaxf(sRed[0], sRed[1]), fmaxf(sRed[2], sRed[3]));
  float e0 = __expf(mysc[0] - m), e1 = __expf(mysc[1] - m);
  sSc[tid] = e0;
  sSc[tid + 256] = e1;
  float s2 = e0 + e1;
  s2 += __shfl_xor(s2, 1);  s2 += __shfl_xor(s2, 2);
  s2 += __shfl_xor(s2, 4);  s2 += __shfl_xor(s2, 8);
  s2 += __shfl_xor(s2, 16); s2 += __shfl_xor(s2, 32);
  if ((tid & 63) == 0) sRed[4 + (tid >> 6)] = s2;
  __syncthreads();
  float l = (sRed[4] + sRed[5]) + (sRed[6] + sRed[7]);

  const int j = tid & 31;
  const int grp = tid >> 5;  // 0..7
  float p = 0.f;
  for (int tt = grp * 64; tt < grp * 64 + 64; ++tt) {
    p += sSc[tt] * ((const float*)(hbase + (size_t)tt * 64))[j];
  }
  sP[grp][j] = p;
  __syncthreads();

  if (tid < H_) {
    float pooled = 0.f;
#pragma unroll
    for (int g = 0; g < 8; ++g) pooled += sP[g][tid];
    pooled /= l;
    float h511 = ((const float*)(hbase + (size_t)511 * 64))[tid];
    float val = h511 * Wdec[tid] + pooled * Wdec[H_ + tid];
    val += __shfl_xor(val, 1);  val += __shfl_xor(val, 2);
    val += __shfl_xor(val, 4);  val += __shfl_xor(val, 8);
    val += __shfl_xor(val, 16);
    if (tid == 0) out[b] = fsig(val + bdec[0]);
  }
}

extern "C" void kernel_launch(void* const* d_in, const int* in_sizes, int n_in,
                              void* d_out, int out_size, void* d_ws, size_t ws_size,
                              hipStream_t stream) {
  const float* x     = (const float*)d_in[0];
  const float* Wenc  = (const float*)d_in[1];
  const float* benc  = (const float*)d_in[2];
  const float* kern  = (const float*)d_in[3];
  const float* rec   = (const float*)d_in[4];
  const float* bias  = (const float*)d_in[5];
  const float* attnW = (const float*)d_in[6];
  const float* attnB = (const float*)d_in[7];
  const float* attnU = (const float*)d_in[8];
  const float* Wdec  = (const float*)d_in[9];
  const float* bdec  = (const float*)d_in[10];

  uint32_t* xg = (uint32_t*)d_ws;  // [B][T][64] packed bf16 pairs = 128 MiB

  hipLaunchKernelGGL(k1_mfma, dim3((B_ * T_) / 128), dim3(256), 0, stream,
                     x, Wenc, benc, kern, bias, xg);
  hipLaunchKernelGGL(k2_scan, dim3(B_ / 2), dim3(64), 0, stream,
                     xg, (float*)d_ws, rec);
  hipLaunchKernelGGL(k3_attn, dim3(B_), dim3(256), 0, stream,
                     xg, attnW, attnB, attnU, Wdec, bdec, (float*)d_out);
}

// Round 13
// 455.617 us; speedup vs baseline: 1.0004x; 1.0004x over previous
//
#include <hip/hip_runtime.h>
#include <stdint.h>

#define B_ 1024
#define T_ 512
#define F_ 64
#define H_ 32
#define G_ 128  // 4H

typedef __attribute__((ext_vector_type(8))) short bf16x8;
typedef __attribute__((ext_vector_type(4))) float f32x4;

__device__ __forceinline__ uint32_t bf16r(float f) {
  uint32_t u = __builtin_bit_cast(uint32_t, f);
  return (u + 0x7fffu + ((u >> 16) & 1u)) >> 16;  // RNE bf16
}
__device__ __forceinline__ float rl(float v, int l) {
  return __builtin_bit_cast(float, __builtin_amdgcn_readlane(__builtin_bit_cast(int, v), l));
}
__device__ __forceinline__ float fsig(float x) { return 1.f / (1.f + __expf(-x)); }
__device__ __forceinline__ float ftanh(float x) { return 2.f / (1.f + __expf(-2.f * x)) - 1.f; }
__device__ __forceinline__ float bflo(uint32_t d) { return __builtin_bit_cast(float, d << 16); }
__device__ __forceinline__ float bfhi(uint32_t d) { return __builtin_bit_cast(float, d & 0xffff0000u); }

#define MFMA16(a, b, c) __builtin_amdgcn_mfma_f32_16x16x32_bf16((a), (b), (c), 0, 0, 0)

// ---------------------------------------------------------------------------
// K1 (MFMA, unchanged — verified r6/r7): xg = pack_bf16(tanh(x@Wenc+benc)@kern+bias)
// ---------------------------------------------------------------------------
__global__ __launch_bounds__(256, 3) void k1_mfma(
    const float* __restrict__ x, const float* __restrict__ Wenc,
    const float* __restrict__ benc, const float* __restrict__ kern,
    const float* __restrict__ bias, uint32_t* __restrict__ xg) {
  __shared__ unsigned short sWt[64 * 72];   // Wenc^T bf16 [n][k], stride 72
  __shared__ unsigned short sKt[128 * 72];  // kern^T bf16 [n][k]
  __shared__ unsigned short sE[128 * 72];   // enc bf16 [row][k]
  const int tid = threadIdx.x;
  const int lane = tid & 63;
  const int w = tid >> 6;       // wave 0..3 -> rows w*32..w*32+31
  const int m = lane & 15;
  const int g = lane >> 4;      // 0..3
  const int r0 = blockIdx.x * 128;

  {  // stage Wenc^T and kern^T as bf16 (one-time)
    const int r = tid & 63;
    const int c0 = (tid >> 6) * 16;
#pragma unroll
    for (int q = 0; q < 4; ++q) {
      float4 v = *(const float4*)(Wenc + (size_t)r * F_ + c0 + q * 4);
      sWt[(c0 + q * 4 + 0) * 72 + r] = (unsigned short)bf16r(v.x);
      sWt[(c0 + q * 4 + 1) * 72 + r] = (unsigned short)bf16r(v.y);
      sWt[(c0 + q * 4 + 2) * 72 + r] = (unsigned short)bf16r(v.z);
      sWt[(c0 + q * 4 + 3) * 72 + r] = (unsigned short)bf16r(v.w);
    }
    const int d0 = (tid >> 6) * 32;
#pragma unroll
    for (int q = 0; q < 8; ++q) {
      float4 v = *(const float4*)(kern + (size_t)r * G_ + d0 + q * 4);
      sKt[(d0 + q * 4 + 0) * 72 + r] = (unsigned short)bf16r(v.x);
      sKt[(d0 + q * 4 + 1) * 72 + r] = (unsigned short)bf16r(v.y);
      sKt[(d0 + q * 4 + 2) * 72 + r] = (unsigned short)bf16r(v.z);
      sKt[(d0 + q * 4 + 3) * 72 + r] = (unsigned short)bf16r(v.w);
    }
  }
  __syncthreads();

  bf16x8 a[2][2];
#pragma unroll
  for (int rt = 0; rt < 2; ++rt)
#pragma unroll
    for (int kh = 0; kh < 2; ++kh) {
      const float* xr = x + (size_t)(r0 + w * 32 + rt * 16 + m) * F_ + kh * 32 + g * 8;
      float4 v0 = ((const float4*)xr)[0];
      float4 v1 = ((const float4*)xr)[1];
      bf16x8 t;
      t[0] = (short)bf16r(v0.x); t[1] = (short)bf16r(v0.y);
      t[2] = (short)bf16r(v0.z); t[3] = (short)bf16r(v0.w);
      t[4] = (short)bf16r(v1.x); t[5] = (short)bf16r(v1.y);
      t[6] = (short)bf16r(v1.z); t[7] = (short)bf16r(v1.w);
      a[rt][kh] = t;
    }

#pragma unroll
  for (int ct = 0; ct < 4; ++ct) {
    float be = benc[ct * 16 + m];
    f32x4 acc0 = {be, be, be, be};
    f32x4 acc1 = {be, be, be, be};
    bf16x8 b0 = *(const bf16x8*)&sWt[(ct * 16 + m) * 72 + g * 8];
    bf16x8 b1 = *(const bf16x8*)&sWt[(ct * 16 + m) * 72 + 32 + g * 8];
    acc0 = MFMA16(a[0][0], b0, acc0);
    acc0 = MFMA16(a[0][1], b1, acc0);
    acc1 = MFMA16(a[1][0], b0, acc1);
    acc1 = MFMA16(a[1][1], b1, acc1);
#pragma unroll
    for (int r4 = 0; r4 < 4; ++r4) {
      sE[(w * 32 + g * 4 + r4) * 72 + ct * 16 + m] =
          (unsigned short)bf16r(ftanh(acc0[r4]));
      sE[(w * 32 + 16 + g * 4 + r4) * 72 + ct * 16 + m] =
          (unsigned short)bf16r(ftanh(acc1[r4]));
    }
  }
  __syncthreads();

  bf16x8 e[2][2];
#pragma unroll
  for (int rt = 0; rt < 2; ++rt)
#pragma unroll
    for (int kh = 0; kh < 2; ++kh)
      e[rt][kh] = *(const bf16x8*)&sE[(w * 32 + rt * 16 + m) * 72 + kh * 32 + g * 8];

#pragma unroll
  for (int ctp = 0; ctp < 4; ++ctp) {
    float blo = bias[ctp * 16 + m];
    float bhi = bias[64 + ctp * 16 + m];
    f32x4 lo0 = {blo, blo, blo, blo}, lo1 = {blo, blo, blo, blo};
    f32x4 hi0 = {bhi, bhi, bhi, bhi}, hi1 = {bhi, bhi, bhi, bhi};
    bf16x8 bl0 = *(const bf16x8*)&sKt[(ctp * 16 + m) * 72 + g * 8];
    bf16x8 bl1 = *(const bf16x8*)&sKt[(ctp * 16 + m) * 72 + 32 + g * 8];
    bf16x8 bh0 = *(const bf16x8*)&sKt[(64 + ctp * 16 + m) * 72 + g * 8];
    bf16x8 bh1 = *(const bf16x8*)&sKt[(64 + ctp * 16 + m) * 72 + 32 + g * 8];
    lo0 = MFMA16(e[0][0], bl0, lo0);  lo0 = MFMA16(e[0][1], bl1, lo0);
    lo1 = MFMA16(e[1][0], bl0, lo1);  lo1 = MFMA16(e[1][1], bl1, lo1);
    hi0 = MFMA16(e[0][0], bh0, hi0);  hi0 = MFMA16(e[0][1], bh1, hi0);
    hi1 = MFMA16(e[1][0], bh0, hi1);  hi1 = MFMA16(e[1][1], bh1, hi1);
#pragma unroll
    for (int r4 = 0; r4 < 4; ++r4) {
      int row0 = r0 + w * 32 + g * 4 + r4;
      xg[(size_t)row0 * 64 + ctp * 16 + m] =
          bf16r(lo0[r4]) | (bf16r(hi0[r4]) << 16);
      int row1 = row0 + 16;
      xg[(size_t)row1 * 64 + ctp * 16 + m] =
          bf16r(lo1[r4]) | (bf16r(hi1[r4]) << 16);
    }
  }
}

// ---------------------------------------------------------------------------
// K2: LSTM scan, TWO batches per wave, chains interleaved. Grid-capped at
// 1 wave/SIMD means latency gaps can only be filled by a second independent
// chain inside the wave (r10: 1700 cyc/step, only 38% VALU issue).
// Per-batch numerics identical to the verified r10 kernel.
// ---------------------------------------------------------------------------
__global__ __launch_bounds__(64, 1) void k2_scan(
    const uint32_t* __restrict__ xgin, float* __restrict__ hout,
    const float* __restrict__ rec) {
  const int lane = threadIdx.x;
  const int b0 = blockIdx.x * 2;
  const bool lo32 = (lane < 32);

  float rA[H_], rB[H_];
#pragma unroll
  for (int k = 0; k < H_; ++k) {
    rA[k] = rec[k * G_ + lane];        // columns 0..63   (i|f)
    rB[k] = rec[k * G_ + 64 + lane];   // columns 64..127 (g|o)
  }

  const uint32_t* xpA = xgin + (size_t)b0 * (T_ * 64) + lane;
  const uint32_t* xpB = xpA + T_ * 64;
  float* hsA = hout + (size_t)b0 * (T_ * 64);
  float* hsB = hsA + T_ * 64;

  float hA = 0.f, cA = 0.f;
  float hB = 0.f, cB = 0.f;

  auto step = [&](uint32_t wA, uint32_t wB, int t) {
    float zA1a = bflo(wA), zA2a = bfhi(wA);
    float zB1a = bflo(wB), zB2a = bfhi(wB);
    float zA1b = 0.f, zA1c = 0.f, zA1d = 0.f;
    float zA2b = 0.f, zA2c = 0.f, zA2d = 0.f;
    float zB1b = 0.f, zB1c = 0.f, zB1d = 0.f;
    float zB2b = 0.f, zB2c = 0.f, zB2d = 0.f;
#pragma unroll
    for (int k4 = 0; k4 < 8; ++k4) {
      float sA0 = rl(hA, 4 * k4 + 0), sB0 = rl(hB, 4 * k4 + 0);
      float sA1 = rl(hA, 4 * k4 + 1), sB1 = rl(hB, 4 * k4 + 1);
      float sA2 = rl(hA, 4 * k4 + 2), sB2 = rl(hB, 4 * k4 + 2);
      float sA3 = rl(hA, 4 * k4 + 3), sB3 = rl(hB, 4 * k4 + 3);
      zA1a = fmaf(sA0, rA[4 * k4 + 0], zA1a); zA2a = fmaf(sA0, rB[4 * k4 + 0], zA2a);
      zB1a = fmaf(sB0, rA[4 * k4 + 0], zB1a); zB2a = fmaf(sB0, rB[4 * k4 + 0], zB2a);
      zA1b = fmaf(sA1, rA[4 * k4 + 1], zA1b); zA2b = fmaf(sA1, rB[4 * k4 + 1], zA2b);
      zB1b = fmaf(sB1, rA[4 * k4 + 1], zB1b); zB2b = fmaf(sB1, rB[4 * k4 + 1], zB2b);
      zA1c = fmaf(sA2, rA[4 * k4 + 2], zA1c); zA2c = fmaf(sA2, rB[4 * k4 + 2], zA2c);
      zB1c = fmaf(sB2, rA[4 * k4 + 2], zB1c); zB2c = fmaf(sB2, rB[4 * k4 + 2], zB2c);
      zA1d = fmaf(sA3, rA[4 * k4 + 3], zA1d); zA2d = fmaf(sA3, rB[4 * k4 + 3], zA2d);
      zB1d = fmaf(sB3, rA[4 * k4 + 3], zB1d); zB2d = fmaf(sB3, rB[4 * k4 + 3], zB2d);
    }
    float zA1 = (zA1a + zA1b) + (zA1c + zA1d);
    float zA2 = (zA2a + zA2b) + (zA2c + zA2d);
    float zB1 = (zB1a + zB1b) + (zB1c + zB1d);
    float zB2 = (zB2a + zB2b) + (zB2c + zB2d);

    float act1A = fsig(zA1);                     // i (lanes<32) | f (lanes>=32)
    float act1B = fsig(zB1);
    float xxA = lo32 ? 2.f * zA2 : zA2;
    float xxB = lo32 ? 2.f * zB2 : zB2;
    float sgA = fsig(xxA);
    float sgB = fsig(xxB);
    float act2A = lo32 ? 2.f * sgA - 1.f : sgA;  // tanh(g) | sigmoid(o)
    float act2B = lo32 ? 2.f * sgB - 1.f : sgB;

    float fA = __shfl(act1A, lane | 32);         // f on all lanes (VERIFIED)
    float fB = __shfl(act1B, lane | 32);
    float oA = __shfl(act2A, lane | 32);         // o on all lanes
    float oB = __shfl(act2B, lane | 32);

    cA = fA * cA + act1A * act2A;                // valid on lanes<32
    cB = fB * cB + act1B * act2B;
    float tcA = ftanh(cA);
    float tcB = ftanh(cB);
    hA = oA * tcA;
    hB = oB * tcB;

    if (lo32) {                                  // fp32 h into dead slot region
      hsA[(size_t)t * 64 + lane] = hA;
      hsB[(size_t)t * 64 + lane] = hB;
    }
  };

  uint32_t pA[4], pB[4];
#pragma unroll
  for (int i = 0; i < 4; ++i) { pA[i] = xpA[i * 64]; pB[i] = xpB[i * 64]; }
  for (int tb = 0; tb < T_; tb += 4) {
    uint32_t nA[4], nB[4];
#pragma unroll
    for (int i = 0; i < 4; ++i) {               // tail wrap reads unused
      nA[i] = xpA[((tb + 4 + i) & 511) * 64];
      nB[i] = xpB[((tb + 4 + i) & 511) * 64];
    }
#pragma unroll
    for (int i = 0; i < 4; ++i) step(pA[i], pB[i], tb + i);
#pragma unroll
    for (int i = 0; i < 4; ++i) { pA[i] = nA[i]; pB[i] = nB[i]; }
  }
}

// ---------------------------------------------------------------------------
// K3 (unchanged — verified r7, spill-free).
// ---------------------------------------------------------------------------
__global__ __launch_bounds__(256, 4) void k3_attn(
    const uint32_t* __restrict__ xg,
    const float* __restrict__ attnW, const float* __restrict__ attnB,
    const float* __restrict__ attnU, const float* __restrict__ Wdec,
    const float* __restrict__ bdec, float* __restrict__ out) {
  __shared__ float sSc[T_];
  __shared__ float sRed[8];
  __shared__ float sP[8][H_];
  const int tid = threadIdx.x;
  const int b = blockIdx.x;

  const uint32_t* hbase = xg + (size_t)b * (T_ * 64);

  float mysc[2];
#pragma unroll
  for (int q = 0; q < 2; ++q) {
    int t = tid + q * 256;
    const float4* hp = (const float4*)(hbase + (size_t)t * 64);

    float hv[H_];
#pragma unroll
    for (int i = 0; i < 8; ++i) {
      float4 v = hp[i];
      hv[4 * i + 0] = v.x; hv[4 * i + 1] = v.y;
      hv[4 * i + 2] = v.z; hv[4 * i + 3] = v.w;
    }

    float lat[H_];
#pragma unroll
    for (int j4 = 0; j4 < 8; ++j4) {
      float4 bv = ((const float4*)attnB)[j4];  // uniform -> s_load
      lat[4 * j4 + 0] = bv.x; lat[4 * j4 + 1] = bv.y;
      lat[4 * j4 + 2] = bv.z; lat[4 * j4 + 3] = bv.w;
    }
#pragma unroll
    for (int d = 0; d < H_; ++d) {
      float hd = hv[d];
      const float4* wr = (const float4*)(attnW + d * H_);  // uniform -> s_load
#pragma unroll
      for (int j4 = 0; j4 < 8; ++j4) {
        float4 w = wr[j4];
        lat[4 * j4 + 0] += hd * w.x;
        lat[4 * j4 + 1] += hd * w.y;
        lat[4 * j4 + 2] += hd * w.z;
        lat[4 * j4 + 3] += hd * w.w;
      }
    }
    float sc = 0.f;
#pragma unroll
    for (int j = 0; j < H_; ++j) sc += ftanh(lat[j]) * attnU[j];
    mysc[q] = sc;
  }

  float m2 = fmaxf(mysc[0], mysc[1]);
  m2 = fmaxf(m2, __shfl_xor(m2, 1));  m2 = fmaxf(m2, __shfl_xor(m2, 2));
  m2 = fmaxf(m2, __shfl_xor(m2, 4));  m2 = fmaxf(m2, __shfl_xor(m2, 8));
  m2 = fmaxf(m2, __shfl_xor(m2, 16)); m2 = fmaxf(m2, __shfl_xor(m2, 32));
  if ((tid & 63) == 0) sRed[tid >> 6] = m2;
  __syncthreads();
  float m = fmaxf(fmaxf(sRed[0], sRed[1]), fmaxf(sRed[2], sRed[3]));
  float e0 = __expf(mysc[0] - m), e1 = __expf(mysc[1] - m);
  sSc[tid] = e0;
  sSc[tid + 256] = e1;
  float s2 = e0 + e1;
  s2 += __shfl_xor(s2, 1);  s2 += __shfl_xor(s2, 2);
  s2 += __shfl_xor(s2, 4);  s2 += __shfl_xor(s2, 8);
  s2 += __shfl_xor(s2, 16); s2 += __shfl_xor(s2, 32);
  if ((tid & 63) == 0) sRed[4 + (tid >> 6)] = s2;
  __syncthreads();
  float l = (sRed[4] + sRed[5]) + (sRed[6] + sRed[7]);

  const int j = tid & 31;
  const int grp = tid >> 5;  // 0..7
  float p = 0.f;
  for (int tt = grp * 64; tt < grp * 64 + 64; ++tt) {
    p += sSc[tt] * ((const float*)(hbase + (size_t)tt * 64))[j];
  }
  sP[grp][j] = p;
  __syncthreads();

  if (tid < H_) {
    float pooled = 0.f;
#pragma unroll
    for (int g = 0; g < 8; ++g) pooled += sP[g][tid];
    pooled /= l;
    float h511 = ((const float*)(hbase + (size_t)511 * 64))[tid];
    float val = h511 * Wdec[tid] + pooled * Wdec[H_ + tid];
    val += __shfl_xor(val, 1);  val += __shfl_xor(val, 2);
    val += __shfl_xor(val, 4);  val += __shfl_xor(val, 8);
    val += __shfl_xor(val, 16);
    if (tid == 0) out[b] = fsig(val + bdec[0]);
  }
}

extern "C" void kernel_launch(void* const* d_in, const int* in_sizes, int n_in,
                              void* d_out, int out_size, void* d_ws, size_t ws_size,
                              hipStream_t stream) {
  const float* x     = (const float*)d_in[0];
  const float* Wenc  = (const float*)d_in[1];
  const float* benc  = (const float*)d_in[2];
  const float* kern  = (const float*)d_in[3];
  const float* rec   = (const float*)d_in[4];
  const float* bias  = (const float*)d_in[5];
  const float* attnW = (const float*)d_in[6];
  const float* attnB = (const float*)d_in[7];
  const float* attnU = (const float*)d_in[8];
  const float* Wdec  = (const float*)d_in[9];
  const float* bdec  = (const float*)d_in[10];

  uint32_t* xg = (uint32_t*)d_ws;  // [B][T][64] packed bf16 pairs = 128 MiB

  hipLaunchKernelGGL(k1_mfma, dim3((B_ * T_) / 128), dim3(256), 0, stream,
                     x, Wenc, benc, kern, bias, xg);
  hipLaunchKernelGGL(k2_scan, dim3(B_ / 2), dim3(64), 0, stream,
                     xg, (float*)d_ws, rec);
  hipLaunchKernelGGL(k3_attn, dim3(B_), dim3(256), 0, stream,
                     xg, attnW, attnB, attnU, Wdec, bdec, (float*)d_out);
}

// Round 14
// 454.865 us; speedup vs baseline: 1.0021x; 1.0017x over previous
//
#include <hip/hip_runtime.h>
#include <stdint.h>

#define B_ 1024
#define T_ 512
#define F_ 64
#define H_ 32
#define G_ 128  // 4H

typedef __attribute__((ext_vector_type(8))) short bf16x8;
typedef __attribute__((ext_vector_type(4))) float f32x4;

__device__ __forceinline__ uint32_t bf16r(float f) {
  uint32_t u = __builtin_bit_cast(uint32_t, f);
  return (u + 0x7fffu + ((u >> 16) & 1u)) >> 16;  // RNE bf16
}
__device__ __forceinline__ float rl(float v, int l) {
  return __builtin_bit_cast(float, __builtin_amdgcn_readlane(__builtin_bit_cast(int, v), l));
}
__device__ __forceinline__ float fsig(float x) { return 1.f / (1.f + __expf(-x)); }
__device__ __forceinline__ float ftanh(float x) { return 2.f / (1.f + __expf(-2.f * x)) - 1.f; }
__device__ __forceinline__ float bflo(uint32_t d) { return __builtin_bit_cast(float, d << 16); }
__device__ __forceinline__ float bfhi(uint32_t d) { return __builtin_bit_cast(float, d & 0xffff0000u); }

#define MFMA16(a, b, c) __builtin_amdgcn_mfma_f32_16x16x32_bf16((a), (b), (c), 0, 0, 0)

// ---------------------------------------------------------------------------
// K1 (MFMA, unchanged — verified r6/r7): xg = pack_bf16(tanh(x@Wenc+benc)@kern+bias)
// ---------------------------------------------------------------------------
__global__ __launch_bounds__(256, 3) void k1_mfma(
    const float* __restrict__ x, const float* __restrict__ Wenc,
    const float* __restrict__ benc, const float* __restrict__ kern,
    const float* __restrict__ bias, uint32_t* __restrict__ xg) {
  __shared__ unsigned short sWt[64 * 72];   // Wenc^T bf16 [n][k], stride 72
  __shared__ unsigned short sKt[128 * 72];  // kern^T bf16 [n][k]
  __shared__ unsigned short sE[128 * 72];   // enc bf16 [row][k]
  const int tid = threadIdx.x;
  const int lane = tid & 63;
  const int w = tid >> 6;       // wave 0..3 -> rows w*32..w*32+31
  const int m = lane & 15;
  const int g = lane >> 4;      // 0..3
  const int r0 = blockIdx.x * 128;

  {  // stage Wenc^T and kern^T as bf16 (one-time)
    const int r = tid & 63;
    const int c0 = (tid >> 6) * 16;
#pragma unroll
    for (int q = 0; q < 4; ++q) {
      float4 v = *(const float4*)(Wenc + (size_t)r * F_ + c0 + q * 4);
      sWt[(c0 + q * 4 + 0) * 72 + r] = (unsigned short)bf16r(v.x);
      sWt[(c0 + q * 4 + 1) * 72 + r] = (unsigned short)bf16r(v.y);
      sWt[(c0 + q * 4 + 2) * 72 + r] = (unsigned short)bf16r(v.z);
      sWt[(c0 + q * 4 + 3) * 72 + r] = (unsigned short)bf16r(v.w);
    }
    const int d0 = (tid >> 6) * 32;
#pragma unroll
    for (int q = 0; q < 8; ++q) {
      float4 v = *(const float4*)(kern + (size_t)r * G_ + d0 + q * 4);
      sKt[(d0 + q * 4 + 0) * 72 + r] = (unsigned short)bf16r(v.x);
      sKt[(d0 + q * 4 + 1) * 72 + r] = (unsigned short)bf16r(v.y);
      sKt[(d0 + q * 4 + 2) * 72 + r] = (unsigned short)bf16r(v.z);
      sKt[(d0 + q * 4 + 3) * 72 + r] = (unsigned short)bf16r(v.w);
    }
  }
  __syncthreads();

  bf16x8 a[2][2];
#pragma unroll
  for (int rt = 0; rt < 2; ++rt)
#pragma unroll
    for (int kh = 0; kh < 2; ++kh) {
      const float* xr = x + (size_t)(r0 + w * 32 + rt * 16 + m) * F_ + kh * 32 + g * 8;
      float4 v0 = ((const float4*)xr)[0];
      float4 v1 = ((const float4*)xr)[1];
      bf16x8 t;
      t[0] = (short)bf16r(v0.x); t[1] = (short)bf16r(v0.y);
      t[2] = (short)bf16r(v0.z); t[3] = (short)bf16r(v0.w);
      t[4] = (short)bf16r(v1.x); t[5] = (short)bf16r(v1.y);
      t[6] = (short)bf16r(v1.z); t[7] = (short)bf16r(v1.w);
      a[rt][kh] = t;
    }

#pragma unroll
  for (int ct = 0; ct < 4; ++ct) {
    float be = benc[ct * 16 + m];
    f32x4 acc0 = {be, be, be, be};
    f32x4 acc1 = {be, be, be, be};
    bf16x8 b0 = *(const bf16x8*)&sWt[(ct * 16 + m) * 72 + g * 8];
    bf16x8 b1 = *(const bf16x8*)&sWt[(ct * 16 + m) * 72 + 32 + g * 8];
    acc0 = MFMA16(a[0][0], b0, acc0);
    acc0 = MFMA16(a[0][1], b1, acc0);
    acc1 = MFMA16(a[1][0], b0, acc1);
    acc1 = MFMA16(a[1][1], b1, acc1);
#pragma unroll
    for (int r4 = 0; r4 < 4; ++r4) {
      sE[(w * 32 + g * 4 + r4) * 72 + ct * 16 + m] =
          (unsigned short)bf16r(ftanh(acc0[r4]));
      sE[(w * 32 + 16 + g * 4 + r4) * 72 + ct * 16 + m] =
          (unsigned short)bf16r(ftanh(acc1[r4]));
    }
  }
  __syncthreads();

  bf16x8 e[2][2];
#pragma unroll
  for (int rt = 0; rt < 2; ++rt)
#pragma unroll
    for (int kh = 0; kh < 2; ++kh)
      e[rt][kh] = *(const bf16x8*)&sE[(w * 32 + rt * 16 + m) * 72 + kh * 32 + g * 8];

#pragma unroll
  for (int ctp = 0; ctp < 4; ++ctp) {
    float blo = bias[ctp * 16 + m];
    float bhi = bias[64 + ctp * 16 + m];
    f32x4 lo0 = {blo, blo, blo, blo}, lo1 = {blo, blo, blo, blo};
    f32x4 hi0 = {bhi, bhi, bhi, bhi}, hi1 = {bhi, bhi, bhi, bhi};
    bf16x8 bl0 = *(const bf16x8*)&sKt[(ctp * 16 + m) * 72 + g * 8];
    bf16x8 bl1 = *(const bf16x8*)&sKt[(ctp * 16 + m) * 72 + 32 + g * 8];
    bf16x8 bh0 = *(const bf16x8*)&sKt[(64 + ctp * 16 + m) * 72 + g * 8];
    bf16x8 bh1 = *(const bf16x8*)&sKt[(64 + ctp * 16 + m) * 72 + 32 + g * 8];
    lo0 = MFMA16(e[0][0], bl0, lo0);  lo0 = MFMA16(e[0][1], bl1, lo0);
    lo1 = MFMA16(e[1][0], bl0, lo1);  lo1 = MFMA16(e[1][1], bl1, lo1);
    hi0 = MFMA16(e[0][0], bh0, hi0);  hi0 = MFMA16(e[0][1], bh1, hi0);
    hi1 = MFMA16(e[1][0], bh0, hi1);  hi1 = MFMA16(e[1][1], bh1, hi1);
#pragma unroll
    for (int r4 = 0; r4 < 4; ++r4) {
      int row0 = r0 + w * 32 + g * 4 + r4;
      xg[(size_t)row0 * 64 + ctp * 16 + m] =
          bf16r(lo0[r4]) | (bf16r(hi0[r4]) << 16);
      int row1 = row0 + 16;
      xg[(size_t)row1 * 64 + ctp * 16 + m] =
          bf16r(lo1[r4]) | (bf16r(hi1[r4]) << 16);
    }
  }
}

// ---------------------------------------------------------------------------
// K2: LSTM scan, TWO batches per wave, chains interleaved. Grid-capped at
// 1 wave/SIMD means latency gaps can only be filled by a second independent
// chain inside the wave (r10: 1700 cyc/step, only 38% VALU issue).
// Per-batch numerics identical to the verified r10 kernel.
// ---------------------------------------------------------------------------
__global__ __launch_bounds__(64, 1) void k2_scan(
    const uint32_t* __restrict__ xgin, float* __restrict__ hout,
    const float* __restrict__ rec) {
  const int lane = threadIdx.x;
  const int b0 = blockIdx.x * 2;
  const bool lo32 = (lane < 32);

  float rA[H_], rB[H_];
#pragma unroll
  for (int k = 0; k < H_; ++k) {
    rA[k] = rec[k * G_ + lane];        // columns 0..63   (i|f)
    rB[k] = rec[k * G_ + 64 + lane];   // columns 64..127 (g|o)
  }

  const uint32_t* xpA = xgin + (size_t)b0 * (T_ * 64) + lane;
  const uint32_t* xpB = xpA + T_ * 64;
  float* hsA = hout + (size_t)b0 * (T_ * 64);
  float* hsB = hsA + T_ * 64;

  float hA = 0.f, cA = 0.f;
  float hB = 0.f, cB = 0.f;

  auto step = [&](uint32_t wA, uint32_t wB, int t) {
    float zA1a = bflo(wA), zA2a = bfhi(wA);
    float zB1a = bflo(wB), zB2a = bfhi(wB);
    float zA1b = 0.f, zA1c = 0.f, zA1d = 0.f;
    float zA2b = 0.f, zA2c = 0.f, zA2d = 0.f;
    float zB1b = 0.f, zB1c = 0.f, zB1d = 0.f;
    float zB2b = 0.f, zB2c = 0.f, zB2d = 0.f;
#pragma unroll
    for (int k4 = 0; k4 < 8; ++k4) {
      float sA0 = rl(hA, 4 * k4 + 0), sB0 = rl(hB, 4 * k4 + 0);
      float sA1 = rl(hA, 4 * k4 + 1), sB1 = rl(hB, 4 * k4 + 1);
      float sA2 = rl(hA, 4 * k4 + 2), sB2 = rl(hB, 4 * k4 + 2);
      float sA3 = rl(hA, 4 * k4 + 3), sB3 = rl(hB, 4 * k4 + 3);
      zA1a = fmaf(sA0, rA[4 * k4 + 0], zA1a); zA2a = fmaf(sA0, rB[4 * k4 + 0], zA2a);
      zB1a = fmaf(sB0, rA[4 * k4 + 0], zB1a); zB2a = fmaf(sB0, rB[4 * k4 + 0], zB2a);
      zA1b = fmaf(sA1, rA[4 * k4 + 1], zA1b); zA2b = fmaf(sA1, rB[4 * k4 + 1], zA2b);
      zB1b = fmaf(sB1, rA[4 * k4 + 1], zB1b); zB2b = fmaf(sB1, rB[4 * k4 + 1], zB2b);
      zA1c = fmaf(sA2, rA[4 * k4 + 2], zA1c); zA2c = fmaf(sA2, rB[4 * k4 + 2], zA2c);
      zB1c = fmaf(sB2, rA[4 * k4 + 2], zB1c); zB2c = fmaf(sB2, rB[4 * k4 + 2], zB2c);
      zA1d = fmaf(sA3, rA[4 * k4 + 3], zA1d); zA2d = fmaf(sA3, rB[4 * k4 + 3], zA2d);
      zB1d = fmaf(sB3, rA[4 * k4 + 3], zB1d); zB2d = fmaf(sB3, rB[4 * k4 + 3], zB2d);
    }
    float zA1 = (zA1a + zA1b) + (zA1c + zA1d);
    float zA2 = (zA2a + zA2b) + (zA2c + zA2d);
    float zB1 = (zB1a + zB1b) + (zB1c + zB1d);
    float zB2 = (zB2a + zB2b) + (zB2c + zB2d);

    float act1A = fsig(zA1);                     // i (lanes<32) | f (lanes>=32)
    float act1B = fsig(zB1);
    float xxA = lo32 ? 2.f * zA2 : zA2;
    float xxB = lo32 ? 2.f * zB2 : zB2;
    float sgA = fsig(xxA);
    float sgB = fsig(xxB);
    float act2A = lo32 ? 2.f * sgA - 1.f : sgA;  // tanh(g) | sigmoid(o)
    float act2B = lo32 ? 2.f * sgB - 1.f : sgB;

    float fA = __shfl(act1A, lane | 32);         // f on all lanes (VERIFIED)
    float fB = __shfl(act1B, lane | 32);
    float oA = __shfl(act2A, lane | 32);         // o on all lanes
    float oB = __shfl(act2B, lane | 32);

    cA = fA * cA + act1A * act2A;                // valid on lanes<32
    cB = fB * cB + act1B * act2B;
    float tcA = ftanh(cA);
    float tcB = ftanh(cB);
    hA = oA * tcA;
    hB = oB * tcB;

    if (lo32) {                                  // fp32 h into dead slot region
      hsA[(size_t)t * 64 + lane] = hA;
      hsB[(size_t)t * 64 + lane] = hB;
    }
  };

  uint32_t pA[4], pB[4];
#pragma unroll
  for (int i = 0; i < 4; ++i) { pA[i] = xpA[i * 64]; pB[i] = xpB[i * 64]; }
  for (int tb = 0; tb < T_; tb += 4) {
    uint32_t nA[4], nB[4];
#pragma unroll
    for (int i = 0; i < 4; ++i) {               // tail wrap reads unused
      nA[i] = xpA[((tb + 4 + i) & 511) * 64];
      nB[i] = xpB[((tb + 4 + i) & 511) * 64];
    }
#pragma unroll
    for (int i = 0; i < 4; ++i) step(pA[i], pB[i], tb + i);
#pragma unroll
    for (int i = 0; i < 4; ++i) { pA[i] = nA[i]; pB[i] = nB[i]; }
  }
}

// ---------------------------------------------------------------------------
// K3 (unchanged — verified r7, spill-free).
// ---------------------------------------------------------------------------
__global__ __launch_bounds__(256, 4) void k3_attn(
    const uint32_t* __restrict__ xg,
    const float* __restrict__ attnW, const float* __restrict__ attnB,
    const float* __restrict__ attnU, const float* __restrict__ Wdec,
    const float* __restrict__ bdec, float* __restrict__ out) {
  __shared__ float sSc[T_];
  __shared__ float sRed[8];
  __shared__ float sP[8][H_];
  const int tid = threadIdx.x;
  const int b = blockIdx.x;

  const uint32_t* hbase = xg + (size_t)b * (T_ * 64);

  float mysc[2];
#pragma unroll
  for (int q = 0; q < 2; ++q) {
    int t = tid + q * 256;
    const float4* hp = (const float4*)(hbase + (size_t)t * 64);

    float hv[H_];
#pragma unroll
    for (int i = 0; i < 8; ++i) {
      float4 v = hp[i];
      hv[4 * i + 0] = v.x; hv[4 * i + 1] = v.y;
      hv[4 * i + 2] = v.z; hv[4 * i + 3] = v.w;
    }

    float lat[H_];
#pragma unroll
    for (int j4 = 0; j4 < 8; ++j4) {
      float4 bv = ((const float4*)attnB)[j4];  // uniform -> s_load
      lat[4 * j4 + 0] = bv.x; lat[4 * j4 + 1] = bv.y;
      lat[4 * j4 + 2] = bv.z; lat[4 * j4 + 3] = bv.w;
    }
#pragma unroll
    for (int d = 0; d < H_; ++d) {
      float hd = hv[d];
      const float4* wr = (const float4*)(attnW + d * H_);  // uniform -> s_load
#pragma unroll
      for (int j4 = 0; j4 < 8; ++j4) {
        float4 w = wr[j4];
        lat[4 * j4 + 0] += hd * w.x;
        lat[4 * j4 + 1] += hd * w.y;
        lat[4 * j4 + 2] += hd * w.z;
        lat[4 * j4 + 3] += hd * w.w;
      }
    }
    float sc = 0.f;
#pragma unroll
    for (int j = 0; j < H_; ++j) sc += ftanh(lat[j]) * attnU[j];
    mysc[q] = sc;
  }

  float m2 = fmaxf(mysc[0], mysc[1]);
  m2 = fmaxf(m2, __shfl_xor(m2, 1));  m2 = fmaxf(m2, __shfl_xor(m2, 2));
  m2 = fmaxf(m2, __shfl_xor(m2, 4));  m2 = fmaxf(m2, __shfl_xor(m2, 8));
  m2 = fmaxf(m2, __shfl_xor(m2, 16)); m2 = fmaxf(m2, __shfl_xor(m2, 32));
  if ((tid & 63) == 0) sRed[tid >> 6] = m2;
  __syncthreads();
  float m = fmaxf(fmaxf(sRed[0], sRed[1]), fmaxf(sRed[2], sRed[3]));
  float e0 = __expf(mysc[0] - m), e1 = __expf(mysc[1] - m);
  sSc[tid] = e0;
  sSc[tid + 256] = e1;
  float s2 = e0 + e1;
  s2 += __shfl_xor(s2, 1);  s2 += __shfl_xor(s2, 2);
  s2 += __shfl_xor(s2, 4);  s2 += __shfl_xor(s2, 8);
  s2 += __shfl_xor(s2, 16); s2 += __shfl_xor(s2, 32);
  if ((tid & 63) == 0) sRed[4 + (tid >> 6)] = s2;
  __syncthreads();
  float l = (sRed[4] + sRed[5]) + (sRed[6] + sRed[7]);

  const int j = tid & 31;
  const int grp = tid >> 5;  // 0..7
  float p = 0.f;
  for (int tt = grp * 64; tt < grp * 64 + 64; ++tt) {
    p += sSc[tt] * ((const float*)(hbase + (size_t)tt * 64))[j];
  }
  sP[grp][j] = p;
  __syncthreads();

  if (tid < H_) {
    float pooled = 0.f;
#pragma unroll
    for (int g = 0; g < 8; ++g) pooled += sP[g][tid];
    pooled /= l;
    float h511 = ((const float*)(hbase + (size_t)511 * 64))[tid];
    float val = h511 * Wdec[tid] + pooled * Wdec[H_ + tid];
    val += __shfl_xor(val, 1);  val += __shfl_xor(val, 2);
    val += __shfl_xor(val, 4);  val += __shfl_xor(val, 8);
    val += __shfl_xor(val, 16);
    if (tid == 0) out[b] = fsig(val + bdec[0]);
  }
}

extern "C" void kernel_launch(void* const* d_in, const int* in_sizes, int n_in,
                              void* d_out, int out_size, void* d_ws, size_t ws_size,
                              hipStream_t stream) {
  const float* x     = (const float*)d_in[0];
  const float* Wenc  = (const float*)d_in[1];
  const float* benc  = (const float*)d_in[2];
  const float* kern  = (const float*)d_in[3];
  const float* rec   = (const float*)d_in[4];
  const float* bias  = (const float*)d_in[5];
  const float* attnW = (const float*)d_in[6];
  const float* attnB = (const float*)d_in[7];
  const float* attnU = (const float*)d_in[8];
  const float* Wdec  = (const float*)d_in[9];
  const float* bdec  = (const float*)d_in[10];

  uint32_t* xg = (uint32_t*)d_ws;  // [B][T][64] packed bf16 pairs = 128 MiB

  hipLaunchKernelGGL(k1_mfma, dim3((B_ * T_) / 128), dim3(256), 0, stream,
                     x, Wenc, benc, kern, bias, xg);
  hipLaunchKernelGGL(k2_scan, dim3(B_ / 2), dim3(64), 0, stream,
                     xg, (float*)d_ws, rec);
  hipLaunchKernelGGL(k3_attn, dim3(B_), dim3(256), 0, stream,
                     xg, attnW, attnB, attnU, Wdec, bdec, (float*)d_out);
}

// Round 15
// 413.074 us; speedup vs baseline: 1.1035x; 1.1012x over previous
//
#include <hip/hip_runtime.h>
#include <stdint.h>

#define B_ 1024
#define T_ 512
#define F_ 64
#define H_ 32
#define G_ 128  // 4H

typedef __attribute__((ext_vector_type(8))) short bf16x8;
typedef __attribute__((ext_vector_type(4))) float f32x4;

__device__ __forceinline__ uint32_t bf16r(float f) {
  uint32_t u = __builtin_bit_cast(uint32_t, f);
  return (u + 0x7fffu + ((u >> 16) & 1u)) >> 16;  // RNE bf16
}
__device__ __forceinline__ float rl(float v, int l) {
  return __builtin_bit_cast(float, __builtin_amdgcn_readlane(__builtin_bit_cast(int, v), l));
}
__device__ __forceinline__ float fsig(float x) { return 1.f / (1.f + __expf(-x)); }
__device__ __forceinline__ float ftanh(float x) { return 2.f / (1.f + __expf(-2.f * x)) - 1.f; }
__device__ __forceinline__ float bflo(uint32_t d) { return __builtin_bit_cast(float, d << 16); }
__device__ __forceinline__ float bfhi(uint32_t d) { return __builtin_bit_cast(float, d & 0xffff0000u); }

#define MFMA16(a, b, c) __builtin_amdgcn_mfma_f32_16x16x32_bf16((a), (b), (c), 0, 0, 0)

// ---------------------------------------------------------------------------
// K1 (MFMA, unchanged — verified r6/r7): xg = pack_bf16(tanh(x@Wenc+benc)@kern+bias)
// ---------------------------------------------------------------------------
__global__ __launch_bounds__(256, 3) void k1_mfma(
    const float* __restrict__ x, const float* __restrict__ Wenc,
    const float* __restrict__ benc, const float* __restrict__ kern,
    const float* __restrict__ bias, uint32_t* __restrict__ xg) {
  __shared__ unsigned short sWt[64 * 72];   // Wenc^T bf16 [n][k], stride 72
  __shared__ unsigned short sKt[128 * 72];  // kern^T bf16 [n][k]
  __shared__ unsigned short sE[128 * 72];   // enc bf16 [row][k]
  const int tid = threadIdx.x;
  const int lane = tid & 63;
  const int w = tid >> 6;       // wave 0..3 -> rows w*32..w*32+31
  const int m = lane & 15;
  const int g = lane >> 4;      // 0..3
  const int r0 = blockIdx.x * 128;

  {  // stage Wenc^T and kern^T as bf16 (one-time)
    const int r = tid & 63;
    const int c0 = (tid >> 6) * 16;
#pragma unroll
    for (int q = 0; q < 4; ++q) {
      float4 v = *(const float4*)(Wenc + (size_t)r * F_ + c0 + q * 4);
      sWt[(c0 + q * 4 + 0) * 72 + r] = (unsigned short)bf16r(v.x);
      sWt[(c0 + q * 4 + 1) * 72 + r] = (unsigned short)bf16r(v.y);
      sWt[(c0 + q * 4 + 2) * 72 + r] = (unsigned short)bf16r(v.z);
      sWt[(c0 + q * 4 + 3) * 72 + r] = (unsigned short)bf16r(v.w);
    }
    const int d0 = (tid >> 6) * 32;
#pragma unroll
    for (int q = 0; q < 8; ++q) {
      float4 v = *(const float4*)(kern + (size_t)r * G_ + d0 + q * 4);
      sKt[(d0 + q * 4 + 0) * 72 + r] = (unsigned short)bf16r(v.x);
      sKt[(d0 + q * 4 + 1) * 72 + r] = (unsigned short)bf16r(v.y);
      sKt[(d0 + q * 4 + 2) * 72 + r] = (unsigned short)bf16r(v.z);
      sKt[(d0 + q * 4 + 3) * 72 + r] = (unsigned short)bf16r(v.w);
    }
  }
  __syncthreads();

  bf16x8 a[2][2];
#pragma unroll
  for (int rt = 0; rt < 2; ++rt)
#pragma unroll
    for (int kh = 0; kh < 2; ++kh) {
      const float* xr = x + (size_t)(r0 + w * 32 + rt * 16 + m) * F_ + kh * 32 + g * 8;
      float4 v0 = ((const float4*)xr)[0];
      float4 v1 = ((const float4*)xr)[1];
      bf16x8 t;
      t[0] = (short)bf16r(v0.x); t[1] = (short)bf16r(v0.y);
      t[2] = (short)bf16r(v0.z); t[3] = (short)bf16r(v0.w);
      t[4] = (short)bf16r(v1.x); t[5] = (short)bf16r(v1.y);
      t[6] = (short)bf16r(v1.z); t[7] = (short)bf16r(v1.w);
      a[rt][kh] = t;
    }

#pragma unroll
  for (int ct = 0; ct < 4; ++ct) {
    float be = benc[ct * 16 + m];
    f32x4 acc0 = {be, be, be, be};
    f32x4 acc1 = {be, be, be, be};
    bf16x8 b0 = *(const bf16x8*)&sWt[(ct * 16 + m) * 72 + g * 8];
    bf16x8 b1 = *(const bf16x8*)&sWt[(ct * 16 + m) * 72 + 32 + g * 8];
    acc0 = MFMA16(a[0][0], b0, acc0);
    acc0 = MFMA16(a[0][1], b1, acc0);
    acc1 = MFMA16(a[1][0], b0, acc1);
    acc1 = MFMA16(a[1][1], b1, acc1);
#pragma unroll
    for (int r4 = 0; r4 < 4; ++r4) {
      sE[(w * 32 + g * 4 + r4) * 72 + ct * 16 + m] =
          (unsigned short)bf16r(ftanh(acc0[r4]));
      sE[(w * 32 + 16 + g * 4 + r4) * 72 + ct * 16 + m] =
          (unsigned short)bf16r(ftanh(acc1[r4]));
    }
  }
  __syncthreads();

  bf16x8 e[2][2];
#pragma unroll
  for (int rt = 0; rt < 2; ++rt)
#pragma unroll
    for (int kh = 0; kh < 2; ++kh)
      e[rt][kh] = *(const bf16x8*)&sE[(w * 32 + rt * 16 + m) * 72 + kh * 32 + g * 8];

#pragma unroll
  for (int ctp = 0; ctp < 4; ++ctp) {
    float blo = bias[ctp * 16 + m];
    float bhi = bias[64 + ctp * 16 + m];
    f32x4 lo0 = {blo, blo, blo, blo}, lo1 = {blo, blo, blo, blo};
    f32x4 hi0 = {bhi, bhi, bhi, bhi}, hi1 = {bhi, bhi, bhi, bhi};
    bf16x8 bl0 = *(const bf16x8*)&sKt[(ctp * 16 + m) * 72 + g * 8];
    bf16x8 bl1 = *(const bf16x8*)&sKt[(ctp * 16 + m) * 72 + 32 + g * 8];
    bf16x8 bh0 = *(const bf16x8*)&sKt[(64 + ctp * 16 + m) * 72 + g * 8];
    bf16x8 bh1 = *(const bf16x8*)&sKt[(64 + ctp * 16 + m) * 72 + 32 + g * 8];
    lo0 = MFMA16(e[0][0], bl0, lo0);  lo0 = MFMA16(e[0][1], bl1, lo0);
    lo1 = MFMA16(e[1][0], bl0, lo1);  lo1 = MFMA16(e[1][1], bl1, lo1);
    hi0 = MFMA16(e[0][0], bh0, hi0);  hi0 = MFMA16(e[0][1], bh1, hi0);
    hi1 = MFMA16(e[1][0], bh0, hi1);  hi1 = MFMA16(e[1][1], bh1, hi1);
#pragma unroll
    for (int r4 = 0; r4 < 4; ++r4) {
      int row0 = r0 + w * 32 + g * 4 + r4;
      xg[(size_t)row0 * 64 + ctp * 16 + m] =
          bf16r(lo0[r4]) | (bf16r(hi0[r4]) << 16);
      int row1 = row0 + 16;
      xg[(size_t)row1 * 64 + ctp * 16 + m] =
          bf16r(lo1[r4]) | (bf16r(hi1[r4]) << 16);
    }
  }
}

// ---------------------------------------------------------------------------
// K2: LSTM scan, 1 batch/wave (1024 waves). Weights held in AGPRs via OPAQUE
// asm defs (v_accvgpr_write) and explicit per-step v_accvgpr_read — the
// compiler cannot rematerialize/reload them from memory (r7/r9/r10/r14:
// allocator pinned VGPR_Count at 48-56 and re-fetched weights every step,
// ~1100 cyc/step of memory waits). Occupancy directive set to exactly
// 1 wave/EU so the full 512-reg budget is available.
// ---------------------------------------------------------------------------
__global__ __attribute__((amdgpu_flat_work_group_size(64, 64)))
__attribute__((amdgpu_waves_per_eu(1, 1)))
void k2_scan(const uint32_t* __restrict__ xgin, float* __restrict__ hout,
             const float* __restrict__ rec) {
  const int lane = threadIdx.x;
  const int b = blockIdx.x;
  const bool lo32 = (lane < 32);

#define DECLW(K) float wa##K, wb##K;
  DECLW(0)  DECLW(1)  DECLW(2)  DECLW(3)  DECLW(4)  DECLW(5)  DECLW(6)  DECLW(7)
  DECLW(8)  DECLW(9)  DECLW(10) DECLW(11) DECLW(12) DECLW(13) DECLW(14) DECLW(15)
  DECLW(16) DECLW(17) DECLW(18) DECLW(19) DECLW(20) DECLW(21) DECLW(22) DECLW(23)
  DECLW(24) DECLW(25) DECLW(26) DECLW(27) DECLW(28) DECLW(29) DECLW(30) DECLW(31)
#undef DECLW

#define STASH(K) { \
    float t0 = rec[K * G_ + lane]; \
    float t1 = rec[K * G_ + 64 + lane]; \
    asm volatile("v_accvgpr_write_b32 %0, %1" : "=a"(wa##K) : "v"(t0)); \
    asm volatile("v_accvgpr_write_b32 %0, %1" : "=a"(wb##K) : "v"(t1)); }
  STASH(0)  STASH(1)  STASH(2)  STASH(3)  STASH(4)  STASH(5)  STASH(6)  STASH(7)
  STASH(8)  STASH(9)  STASH(10) STASH(11) STASH(12) STASH(13) STASH(14) STASH(15)
  STASH(16) STASH(17) STASH(18) STASH(19) STASH(20) STASH(21) STASH(22) STASH(23)
  STASH(24) STASH(25) STASH(26) STASH(27) STASH(28) STASH(29) STASH(30) STASH(31)
#undef STASH

  const uint32_t* xp = xgin + (size_t)b * (T_ * 64) + lane;
  float* hst = hout + (size_t)b * (T_ * 64);

  float h = 0.f, c = 0.f;

  auto step = [&](uint32_t w, int t) {
    float z1a = bflo(w);   // z[lane]       (i|f pre-act)
    float z2a = bfhi(w);   // z[lane+64]    (g|o pre-act)
    float z1b = 0.f, z1c = 0.f, z1d = 0.f;
    float z2b = 0.f, z2c = 0.f, z2d = 0.f;
#define AC(K, S) { float s = rl(h, K); float va, vb; \
    asm volatile("v_accvgpr_read_b32 %0, %1" : "=v"(va) : "a"(wa##K)); \
    asm volatile("v_accvgpr_read_b32 %0, %1" : "=v"(vb) : "a"(wb##K)); \
    z1##S = fmaf(s, va, z1##S); \
    z2##S = fmaf(s, vb, z2##S); }
    AC(0, a)  AC(1, b)  AC(2, c)  AC(3, d)
    AC(4, a)  AC(5, b)  AC(6, c)  AC(7, d)
    AC(8, a)  AC(9, b)  AC(10, c) AC(11, d)
    AC(12, a) AC(13, b) AC(14, c) AC(15, d)
    AC(16, a) AC(17, b) AC(18, c) AC(19, d)
    AC(20, a) AC(21, b) AC(22, c) AC(23, d)
    AC(24, a) AC(25, b) AC(26, c) AC(27, d)
    AC(28, a) AC(29, b) AC(30, c) AC(31, d)
#undef AC
    float z1 = (z1a + z1b) + (z1c + z1d);
    float z2 = (z2a + z2b) + (z2c + z2d);

    float act1 = fsig(z1);                       // i (lanes<32) | f (lanes>=32)
    float xx = lo32 ? 2.f * z2 : z2;
    float sg = fsig(xx);
    float act2 = lo32 ? 2.f * sg - 1.f : sg;     // tanh(g) | sigmoid(o)

    float f_all = __shfl(act1, lane | 32);       // f on all lanes (VERIFIED)
    float o_all = __shfl(act2, lane | 32);       // o on all lanes

    c = f_all * c + act1 * act2;                 // valid on lanes<32
    float tc = ftanh(c);
    h = o_all * tc;

    if (lo32) hst[(size_t)t * 64 + lane] = h;    // fp32 h into dead slot region
  };

  uint32_t p[8];
#pragma unroll
  for (int i = 0; i < 8; ++i) p[i] = xp[i * 64];
  for (int tb = 0; tb < T_; tb += 8) {
    uint32_t n[8];
#pragma unroll
    for (int i = 0; i < 8; ++i) n[i] = xp[((tb + 8 + i) & 511) * 64];  // tail wrap unused
#pragma unroll
    for (int i = 0; i < 8; ++i) step(p[i], tb + i);
#pragma unroll
    for (int i = 0; i < 8; ++i) p[i] = n[i];
  }
}

// ---------------------------------------------------------------------------
// K3 (unchanged — verified r7, spill-free).
// ---------------------------------------------------------------------------
__global__ __launch_bounds__(256, 4) void k3_attn(
    const uint32_t* __restrict__ xg,
    const float* __restrict__ attnW, const float* __restrict__ attnB,
    const float* __restrict__ attnU, const float* __restrict__ Wdec,
    const float* __restrict__ bdec, float* __restrict__ out) {
  __shared__ float sSc[T_];
  __shared__ float sRed[8];
  __shared__ float sP[8][H_];
  const int tid = threadIdx.x;
  const int b = blockIdx.x;

  const uint32_t* hbase = xg + (size_t)b * (T_ * 64);

  float mysc[2];
#pragma unroll
  for (int q = 0; q < 2; ++q) {
    int t = tid + q * 256;
    const float4* hp = (const float4*)(hbase + (size_t)t * 64);

    float hv[H_];
#pragma unroll
    for (int i = 0; i < 8; ++i) {
      float4 v = hp[i];
      hv[4 * i + 0] = v.x; hv[4 * i + 1] = v.y;
      hv[4 * i + 2] = v.z; hv[4 * i + 3] = v.w;
    }

    float lat[H_];
#pragma unroll
    for (int j4 = 0; j4 < 8; ++j4) {
      float4 bv = ((const float4*)attnB)[j4];  // uniform -> s_load
      lat[4 * j4 + 0] = bv.x; lat[4 * j4 + 1] = bv.y;
      lat[4 * j4 + 2] = bv.z; lat[4 * j4 + 3] = bv.w;
    }
#pragma unroll
    for (int d = 0; d < H_; ++d) {
      float hd = hv[d];
      const float4* wr = (const float4*)(attnW + d * H_);  // uniform -> s_load
#pragma unroll
      for (int j4 = 0; j4 < 8; ++j4) {
        float4 w = wr[j4];
        lat[4 * j4 + 0] += hd * w.x;
        lat[4 * j4 + 1] += hd * w.y;
        lat[4 * j4 + 2] += hd * w.z;
        lat[4 * j4 + 3] += hd * w.w;
      }
    }
    float sc = 0.f;
#pragma unroll
    for (int j = 0; j < H_; ++j) sc += ftanh(lat[j]) * attnU[j];
    mysc[q] = sc;
  }

  float m2 = fmaxf(mysc[0], mysc[1]);
  m2 = fmaxf(m2, __shfl_xor(m2, 1));  m2 = fmaxf(m2, __shfl_xor(m2, 2));
  m2 = fmaxf(m2, __shfl_xor(m2, 4));  m2 = fmaxf(m2, __shfl_xor(m2, 8));
  m2 = fmaxf(m2, __shfl_xor(m2, 16)); m2 = fmaxf(m2, __shfl_xor(m2, 32));
  if ((tid & 63) == 0) sRed[tid >> 6] = m2;
  __syncthreads();
  float m = fmaxf(fmaxf(sRed[0], sRed[1]), fmaxf(sRed[2], sRed[3]));
  float e0 = __expf(mysc[0] - m), e1 = __expf(mysc[1] - m);
  sSc[tid] = e0;
  sSc[tid + 256] = e1;
  float s2 = e0 + e1;
  s2 += __shfl_xor(s2, 1);  s2 += __shfl_xor(s2, 2);
  s2 += __shfl_xor(s2, 4);  s2 += __shfl_xor(s2, 8);
  s2 += __shfl_xor(s2, 16); s2 += __shfl_xor(s2, 32);
  if ((tid & 63) == 0) sRed[4 + (tid >> 6)] = s2;
  __syncthreads();
  float l = (sRed[4] + sRed[5]) + (sRed[6] + sRed[7]);

  const int j = tid & 31;
  const int grp = tid >> 5;  // 0..7
  float p = 0.f;
  for (int tt = grp * 64; tt < grp * 64 + 64; ++tt) {
    p += sSc[tt] * ((const float*)(hbase + (size_t)tt * 64))[j];
  }
  sP[grp][j] = p;
  __syncthreads();

  if (tid < H_) {
    float pooled = 0.f;
#pragma unroll
    for (int g = 0; g < 8; ++g) pooled += sP[g][tid];
    pooled /= l;
    float h511 = ((const float*)(hbase + (size_t)511 * 64))[tid];
    float val = h511 * Wdec[tid] + pooled * Wdec[H_ + tid];
    val += __shfl_xor(val, 1);  val += __shfl_xor(val, 2);
    val += __shfl_xor(val, 4);  val += __shfl_xor(val, 8);
    val += __shfl_xor(val, 16);
    if (tid == 0) out[b] = fsig(val + bdec[0]);
  }
}

extern "C" void kernel_launch(void* const* d_in, const int* in_sizes, int n_in,
                              void* d_out, int out_size, void* d_ws, size_t ws_size,
                              hipStream_t stream) {
  const float* x     = (const float*)d_in[0];
  const float* Wenc  = (const float*)d_in[1];
  const float* benc  = (const float*)d_in[2];
  const float* kern  = (const float*)d_in[3];
  const float* rec   = (const float*)d_in[4];
  const float* bias  = (const float*)d_in[5];
  const float* attnW = (const float*)d_in[6];
  const float* attnB = (const float*)d_in[7];
  const float* attnU = (const float*)d_in[8];
  const float* Wdec  = (const float*)d_in[9];
  const float* bdec  = (const float*)d_in[10];

  uint32_t* xg = (uint32_t*)d_ws;  // [B][T][64] packed bf16 pairs = 128 MiB

  hipLaunchKernelGGL(k1_mfma, dim3((B_ * T_) / 128), dim3(256), 0, stream,
                     x, Wenc, benc, kern, bias, xg);
  hipLaunchKernelGGL(k2_scan, dim3(B_), dim3(64), 0, stream,
                     xg, (float*)d_ws, rec);
  hipLaunchKernelGGL(k3_attn, dim3(B_), dim3(256), 0, stream,
                     xg, attnW, attnB, attnU, Wdec, bdec, (float*)d_out);
}